// Round 1
// baseline (283.929 us; speedup 1.0000x reference)
//
#include <hip/hip_runtime.h>
#include <hip/hip_bf16.h>
#include <math.h>

// Problem constants
#define H   1024
#define Dd  200
#define Dp  208      // D padded to 13 * 16
#define Kc  8
#define Bb  8
#define Ll  4096
#define Mm  (Bb*Ll)  // 32768 rows
#define BM  64
#define BK  64
#define NT  13       // N tiles of 16 (208 cols)
#define KT  (H/BK)   // 16 k-iters

typedef __attribute__((ext_vector_type(8))) short short8;
typedef __attribute__((ext_vector_type(4))) float f32x4;

// ws layout (bytes)
#define OFF_W1T 0                          // bf16 [Dp][H] = 425984 B
#define OFF_S   425984                     // f32 [Mm][Kc] = 1048576 B
#define OFF_SEG (425984 + Mm*Kc*4)         // f32 [Bb][16][Kc] = 4096 B
#define WS_NEEDED (OFF_SEG + Bb*16*Kc*4)

__device__ __forceinline__ unsigned short f2bf(float x){
  unsigned u = __float_as_uint(x);
  unsigned r = (u + 0x7FFFu + ((u >> 16) & 1u)) >> 16;   // RNE
  return (unsigned short)r;
}

// ---------------- prep: W1 (fp32 [H][Dd]) -> W1T (bf16 [Dp][H], zero-padded cols)
__global__ __launch_bounds__(256) void prep_w1t(const float* __restrict__ W1,
                                                unsigned short* __restrict__ W1T){
  int idx = blockIdx.x * 256 + threadIdx.x;   // 0 .. Dp*H-1
  int d = idx >> 10;
  int h = idx & 1023;
  float v = (d < Dd) ? W1[h * Dd + d] : 0.f;
  W1T[idx] = f2bf(v);
}

// ---------------- fused GEMM1 (bf16 MFMA) + tanh + GEMM2 + mean-scale -> s
__global__ __launch_bounds__(256) void gemm_fused(const float* __restrict__ hidd,
                                                  const unsigned short* __restrict__ W1T,
                                                  const float* __restrict__ b1,
                                                  const float* __restrict__ W2,
                                                  const float* __restrict__ b2,
                                                  float* __restrict__ sOut){
  __shared__ unsigned short lA[BM * BK];   // swizzled, [row][k]
  __shared__ unsigned short lB[Dp * BK];   // swizzled, [col][k]  (B^T layout)
  __shared__ float lrow[BM];
  __shared__ float lW2[Dp * Kc];
  __shared__ float lb1[Dp];
  char* lAc = (char*)lA;
  char* lBc = (char*)lB;

  const int tid  = threadIdx.x;
  const int lane = tid & 63;
  const int wid  = tid >> 6;
  const int lc   = lane & 15;
  const int lg   = lane >> 4;
  const int wrow0 = wid * 16;
  const long rowBase = (long)blockIdx.x * BM;

  // stage b1 / W2 into LDS (padded with zeros)
  if (tid < Dp) lb1[tid] = (tid < Dd) ? b1[tid] : 0.f;
  for (int g = tid; g < Dp * Kc; g += 256){
    int dcol = g >> 3;
    lW2[g] = (dcol < Dd) ? W2[g] : 0.f;
  }
  float b2r[Kc];
  #pragma unroll
  for (int k = 0; k < Kc; ++k) b2r[k] = b2[k];

  f32x4 acc[NT];
  #pragma unroll
  for (int t = 0; t < NT; ++t) acc[t] = (f32x4){0.f, 0.f, 0.f, 0.f};

  float mpart[4] = {0.f, 0.f, 0.f, 0.f};

  const int rowA  = wrow0 + lc;
  const int aswz  = (rowA & 7) << 4;
  const int bswz  = (lc & 7) << 4;   // (colb&7)==(lc&7) since colb = 16t+lc

  for (int kt = 0; kt < KT; ++kt){
    // ---- stage A: 64 rows x 64 k, fp32 -> bf16, swizzled; accumulate row sums
    #pragma unroll
    for (int i = 0; i < 4; ++i){
      int idx = i * 256 + tid;
      int row = idx >> 4;
      int hl  = (idx & 15) * 4;      // local k (float index), multiple of 4
      const float4 v = *(const float4*)(hidd + (rowBase + row) * H + kt * BK + hl);
      mpart[i] += v.x + v.y + v.z + v.w;
      ushort4 pk;
      pk.x = f2bf(v.x); pk.y = f2bf(v.y); pk.z = f2bf(v.z); pk.w = f2bf(v.w);
      int off = (row * 128) + ((hl * 2) ^ ((row & 7) << 4));
      *(ushort4*)(lAc + off) = pk;
    }
    // ---- stage B: 208 cols x 64 k bf16 from W1T, swizzled
    #pragma unroll
    for (int j = 0; j < 7; ++j){
      int g = j * 256 + tid;
      if (g < Dp * 8){
        int col = g >> 3;
        int kc  = (g & 7) * 8;
        uint4 v = *(const uint4*)(W1T + col * H + kt * BK + kc);
        int off = (col * 128) + ((kc * 2) ^ ((col & 7) << 4));
        *(uint4*)(lBc + off) = v;
      }
    }
    __syncthreads();
    // ---- MFMA: 2 k-slices x 13 N-tiles
    #pragma unroll
    for (int ks = 0; ks < 2; ++ks){
      int k0 = ks * 32 + lg * 8;
      const short8 af = *(const short8*)(lAc + rowA * 128 + ((k0 * 2) ^ aswz));
      #pragma unroll
      for (int t = 0; t < NT; ++t){
        int colb = t * 16 + lc;
        const short8 bfr = *(const short8*)(lBc + colb * 128 + ((k0 * 2) ^ bswz));
        acc[t] = __builtin_amdgcn_mfma_f32_16x16x32_bf16(af, bfr, acc[t], 0, 0, 0);
      }
    }
    __syncthreads();
  }

  // ---- row means: reduce mpart over the 16 threads sharing (tid>>4)
  #pragma unroll
  for (int i = 0; i < 4; ++i){
    float v = mpart[i];
    v += __shfl_xor(v, 1); v += __shfl_xor(v, 2);
    v += __shfl_xor(v, 4); v += __shfl_xor(v, 8);
    if ((tid & 15) == 0) lrow[i * 16 + (tid >> 4)] = v;
  }
  __syncthreads();

  // ---- epilogue: tanh + GEMM2 (in-register) + butterfly reduce + scale by mean
  float part[4][Kc];
  #pragma unroll
  for (int r = 0; r < 4; ++r)
    #pragma unroll
    for (int k = 0; k < Kc; ++k) part[r][k] = 0.f;

  #pragma unroll
  for (int t = 0; t < NT; ++t){
    int col = t * 16 + lc;
    float b1v = lb1[col];
    float w2v[Kc];
    #pragma unroll
    for (int k = 0; k < Kc; ++k) w2v[k] = lW2[col * Kc + k];
    #pragma unroll
    for (int r = 0; r < 4; ++r){
      float a = tanhf(acc[t][r] + b1v);
      #pragma unroll
      for (int k = 0; k < Kc; ++k) part[r][k] = fmaf(a, w2v[k], part[r][k]);
    }
  }
  #pragma unroll
  for (int m = 1; m < 16; m <<= 1){
    #pragma unroll
    for (int r = 0; r < 4; ++r)
      #pragma unroll
      for (int k = 0; k < Kc; ++k)
        part[r][k] += __shfl_xor(part[r][k], m);
  }
  if (lc == 0){
    #pragma unroll
    for (int r = 0; r < 4; ++r){
      int rloc = wrow0 + lg * 4 + r;
      long grow = rowBase + rloc;
      float mr = lrow[rloc] * (1.0f / 1024.0f);
      float4 o0, o1;
      o0.x = (part[r][0] + b2r[0]) * mr;
      o0.y = (part[r][1] + b2r[1]) * mr;
      o0.z = (part[r][2] + b2r[2]) * mr;
      o0.w = (part[r][3] + b2r[3]) * mr;
      o1.x = (part[r][4] + b2r[4]) * mr;
      o1.y = (part[r][5] + b2r[5]) * mr;
      o1.z = (part[r][6] + b2r[6]) * mr;
      o1.w = (part[r][7] + b2r[7]) * mr;
      *(float4*)(sOut + grow * Kc)     = o0;
      *(float4*)(sOut + grow * Kc + 4) = o1;
    }
  }
}

// ---------------- per-(batch,segment) channel sums
__global__ __launch_bounds__(256) void seg_sum(const float* __restrict__ s,
                                               float* __restrict__ segs){
  int b   = blockIdx.x >> 4;
  int seg = blockIdx.x & 15;
  int tid = threadIdx.x, lane = tid & 63, wid = tid >> 6;
  int l = seg * 256 + tid;
  const float4* sp = (const float4*)(s + ((long)(b * Ll + l)) * Kc);
  float4 v0 = sp[0], v1 = sp[1];
  float v[8] = {v0.x, v0.y, v0.z, v0.w, v1.x, v1.y, v1.z, v1.w};
  #pragma unroll
  for (int k = 0; k < 8; ++k){
    float x = v[k];
    x += __shfl_xor(x, 1);  x += __shfl_xor(x, 2);  x += __shfl_xor(x, 4);
    x += __shfl_xor(x, 8);  x += __shfl_xor(x, 16); x += __shfl_xor(x, 32);
    v[k] = x;
  }
  __shared__ float part[4][8];
  if (lane == 0){
    #pragma unroll
    for (int k = 0; k < 8; ++k) part[wid][k] = v[k];
  }
  __syncthreads();
  if (tid < 8){
    float t = part[0][tid] + part[1][tid] + part[2][tid] + part[3][tid];
    segs[(b * 16 + seg) * 8 + tid] = t;
  }
}

// ---------------- scan + det + softmax + log_softmax + pick + loss
__global__ __launch_bounds__(256) void scan_loss(const float* __restrict__ s,
                                                 const float* __restrict__ segs,
                                                 const int* __restrict__ ptypes,
                                                 const int* __restrict__ labels,
                                                 float* __restrict__ out){
  int b   = blockIdx.x >> 4;
  int seg = blockIdx.x & 15;
  int tid = threadIdx.x, lane = tid & 63, wid = tid >> 6;
  int l = seg * 256 + tid;

  float carry[8], T[8];
  #pragma unroll
  for (int k = 0; k < 8; ++k){ carry[k] = 0.f; T[k] = 0.f; }
  for (int ss = 0; ss < 16; ++ss){
    #pragma unroll
    for (int k = 0; k < 8; ++k){
      float x = segs[(b * 16 + ss) * 8 + k];
      T[k] += x;
      if (ss < seg) carry[k] += x;
    }
  }

  const float4* sp = (const float4*)(s + ((long)(b * Ll + l)) * Kc);
  float4 v0 = sp[0], v1 = sp[1];
  float sv[8] = {v0.x, v0.y, v0.z, v0.w, v1.x, v1.y, v1.z, v1.w};
  float P[8];
  #pragma unroll
  for (int k = 0; k < 8; ++k) P[k] = sv[k];

  // inclusive scan within wave, per channel
  #pragma unroll
  for (int st = 1; st < 64; st <<= 1){
    #pragma unroll
    for (int k = 0; k < 8; ++k){
      float u = __shfl_up(P[k], st);
      if (lane >= st) P[k] += u;
    }
  }
  __shared__ float wsum[4][8];
  if (lane == 63){
    #pragma unroll
    for (int k = 0; k < 8; ++k) wsum[wid][k] = P[k];
  }
  __syncthreads();
  for (int w = 0; w < wid; ++w){
    #pragma unroll
    for (int k = 0; k < 8; ++k) P[k] += wsum[w][k];
  }
  #pragma unroll
  for (int k = 0; k < 8; ++k) P[k] += carry[k];

  int pt = ptypes[b];
  float det[8];
  if (pt == 0){
    float inv = 1.0f / (float)(l + 1);
    #pragma unroll
    for (int k = 0; k < 8; ++k) det[k] = P[k] * inv;
  } else if (pt == 1){
    float inv = 1.0f / (float)(Ll - l);
    #pragma unroll
    for (int k = 0; k < 8; ++k) det[k] = (T[k] - P[k] + sv[k]) * inv;
  } else {
    #pragma unroll
    for (int k = 0; k < 8; ++k) det[k] = sv[k];
  }

  // softmax
  float mx = det[0];
  #pragma unroll
  for (int k = 1; k < 8; ++k) mx = fmaxf(mx, det[k]);
  float e[8], Z = 0.f;
  #pragma unroll
  for (int k = 0; k < 8; ++k){ e[k] = expf(det[k] - mx); Z += e[k]; }
  float invZ = 1.0f / Z;
  float p[8];
  #pragma unroll
  for (int k = 0; k < 8; ++k) p[k] = e[k] * invZ;
  // log_softmax of p
  float mx2 = p[0];
  #pragma unroll
  for (int k = 1; k < 8; ++k) mx2 = fmaxf(mx2, p[k]);
  float Z2 = 0.f;
  #pragma unroll
  for (int k = 0; k < 8; ++k) Z2 += expf(p[k] - mx2);
  float lse = logf(Z2) + mx2;

  int lab = labels[b * Ll + l];
  float picked = 0.f;
  #pragma unroll
  for (int k = 0; k < 8; ++k) picked = (lab == k) ? (p[k] - lse) : picked;

  // block reduce and accumulate
  float a = picked;
  a += __shfl_xor(a, 1);  a += __shfl_xor(a, 2);  a += __shfl_xor(a, 4);
  a += __shfl_xor(a, 8);  a += __shfl_xor(a, 16); a += __shfl_xor(a, 32);
  __shared__ float red[4];
  if (lane == 0) red[wid] = a;
  __syncthreads();
  if (tid == 0){
    float tot = red[0] + red[1] + red[2] + red[3];
    atomicAdd(out + b, -tot * (1.0f / (float)Ll));
  }
}

extern "C" void kernel_launch(void* const* d_in, const int* in_sizes, int n_in,
                              void* d_out, int out_size, void* d_ws, size_t ws_size,
                              hipStream_t stream){
  const float* hidd  = (const float*)d_in[0];
  const float* W1    = (const float*)d_in[1];
  const float* b1    = (const float*)d_in[2];
  const float* W2    = (const float*)d_in[3];
  const float* b2    = (const float*)d_in[4];
  const int* ptypes  = (const int*)d_in[5];
  const int* labels  = (const int*)d_in[6];
  float* out = (float*)d_out;
  char* ws = (char*)d_ws;
  if (ws_size < (size_t)WS_NEEDED) return;

  unsigned short* W1T = (unsigned short*)(ws + OFF_W1T);
  float* s    = (float*)(ws + OFF_S);
  float* segs = (float*)(ws + OFF_SEG);

  prep_w1t<<<(Dp * H) / 256, 256, 0, stream>>>(W1, W1T);
  gemm_fused<<<Mm / BM, 256, 0, stream>>>(hidd, W1T, b1, W2, b2, s);
  seg_sum<<<Bb * 16, 256, 0, stream>>>(s, segs);
  hipMemsetAsync(d_out, 0, Bb * sizeof(float), stream);
  scan_loss<<<Bb * 16, 256, 0, stream>>>(s, segs, ptypes, labels, out);
}